// Round 10
// baseline (897.108 us; speedup 1.0000x reference)
//
#include <hip/hip_runtime.h>
#include <hip/hip_bf16.h>
#include <cstddef>

typedef signed char i8;
typedef unsigned char u8;
typedef unsigned int u32;
typedef int intx4 __attribute__((ext_vector_type(4)));
typedef float floatx4 __attribute__((ext_vector_type(4)));
typedef short shortx4 __attribute__((ext_vector_type(4)));

#define T_STEPS 500
#define BATCH 64
#define INDIM 440
#define INPAD 512   // i8 K-pad for layer-0 GEMM (BK=128)
#define HID 1024
#define OUTDIM 1944
#define OUTPAD 2048
#define NBF 31      // final col-blocks: 31*64=1984 >= 1944 (saves 1/32 of work)
#define MROWS 32000  // T*B
#define INV_SQRT_BN 0.9999950000374997f  // 1/sqrt(1+1e-5)
#define CH 20        // scan chunk: 500 = 25*20
// ws fixed-point: 24-bit (i16 hi + u8 lo), scale 2^19, range +-16 (=20 sigma).
// eps <= 2^-20 -> cumulative-drive error ~0.004 spikes: numerically a no-op,
// but cuts the GEMM->LIF round trip from 8B/elem to 6B/elem.
#define WS_SCALE 524288.f
#define WS_INV (1.f / 524288.f)
#define WS_CLAMP 15.99994f

__device__ __forceinline__ void g2lds16(const void* g, void* l) {
  __builtin_amdgcn_global_load_lds(
      (const __attribute__((address_space(1))) u32*)g,
      (__attribute__((address_space(3))) u32*)l, 16, 0, 0);
}

// ---------------- input FSQ scan: xs [T,B,440] -> spikes i8 [T*B, 512] ----
__global__ __launch_bounds__(256) void input_fsq_k(const float* __restrict__ xs,
                                                   i8* __restrict__ sp0) {
  int tid = blockIdx.x * 256 + threadIdx.x;  // 64*512
  int b = tid >> 9;
  int i = tid & 511;
  bool act = (i < INDIM);
  const float* src = xs + (size_t)b * INDIM + (act ? i : (INDIM - 1));
  i8* dst = sp0 + (size_t)b * INPAD + i;
  float fact = act ? 1.f : 0.f;
  const int LS = BATCH * INDIM;
  const int SS = BATCH * INPAD;
  float vmem = 0.f;
  float bufA[CH], bufB[CH];
#pragma unroll
  for (int j = 0; j < CH; ++j) bufA[j] = src[(size_t)j * LS];
  for (int it = 0; it < 12; ++it) {
    const int t0 = it * 2 * CH;
#pragma unroll
    for (int j = 0; j < CH; ++j) bufB[j] = src[(size_t)(t0 + CH + j) * LS];
#pragma unroll
    for (int j = 0; j < CH; ++j) {
      vmem += bufA[j] * fact;
      float q = fminf(fmaxf(rintf(vmem), 0.f), 7.f);
      vmem -= q;
      dst[(size_t)(t0 + j) * SS] = (i8)q;
    }
#pragma unroll
    for (int j = 0; j < CH; ++j) bufA[j] = src[(size_t)(t0 + 2 * CH + j) * LS];
#pragma unroll
    for (int j = 0; j < CH; ++j) {
      vmem += bufB[j] * fact;
      float q = fminf(fmaxf(rintf(vmem), 0.f), 7.f);
      vmem -= q;
      dst[(size_t)(t0 + CH + j) * SS] = (i8)q;
    }
  }
  const int t0 = 24 * CH;
#pragma unroll
  for (int j = 0; j < CH; ++j) {
    vmem += bufA[j] * fact;
    float q = fminf(fmaxf(rintf(vmem), 0.f), 7.f);
    vmem -= q;
    dst[(size_t)(t0 + j) * SS] = (i8)q;
  }
}

// ---------------- LIF scan: ws fixed24 [T*B, 1024] -> spikes i8 ----
__global__ __launch_bounds__(256) void lif_k(const short* __restrict__ w16,
                                             const u8* __restrict__ w8,
                                             const float* __restrict__ taus,
                                             i8* __restrict__ sp) {
  int tid = blockIdx.x * 256 + threadIdx.x;  // 65536 = B*HID
  float tau = taus[tid & (HID - 1)];
  const short* p16 = w16 + tid;
  const u8* p8 = w8 + tid;
  i8* dst = sp + tid;
  const int S = BATCH * HID;
  float syn = 0.f, vmem = 0.f;
  int a16[CH], b16[CH];
  int a8[CH], b8[CH];
#pragma unroll
  for (int j = 0; j < CH; ++j) {
    a16[j] = p16[(size_t)j * S];
    a8[j] = p8[(size_t)j * S];
  }
  for (int it = 0; it < 12; ++it) {
    const int t0 = it * 2 * CH;
#pragma unroll
    for (int j = 0; j < CH; ++j) {
      b16[j] = p16[(size_t)(t0 + CH + j) * S];
      b8[j] = p8[(size_t)(t0 + CH + j) * S];
    }
#pragma unroll
    for (int j = 0; j < CH; ++j) {
      float w = (float)(a16[j] * 256 + a8[j]) * WS_INV;
      syn = fmaf(tau, syn, w);
      vmem += syn;
      float q = fminf(fmaxf(rintf(vmem), 0.f), 7.f);
      vmem -= q;
      dst[(size_t)(t0 + j) * S] = (i8)q;
    }
#pragma unroll
    for (int j = 0; j < CH; ++j) {
      a16[j] = p16[(size_t)(t0 + 2 * CH + j) * S];
      a8[j] = p8[(size_t)(t0 + 2 * CH + j) * S];
    }
#pragma unroll
    for (int j = 0; j < CH; ++j) {
      float w = (float)(b16[j] * 256 + b8[j]) * WS_INV;
      syn = fmaf(tau, syn, w);
      vmem += syn;
      float q = fminf(fmaxf(rintf(vmem), 0.f), 7.f);
      vmem -= q;
      dst[(size_t)(t0 + CH + j) * S] = (i8)q;
    }
  }
  const int t0 = 24 * CH;
#pragma unroll
  for (int j = 0; j < CH; ++j) {
    float w = (float)(a16[j] * 256 + a8[j]) * WS_INV;
    syn = fmaf(tau, syn, w);
    vmem += syn;
    float q = fminf(fmaxf(rintf(vmem), 0.f), 7.f);
    vmem -= q;
    dst[(size_t)(t0 + j) * S] = (i8)q;
  }
}

// ---------------- weight prep: fold BN gamma, dual int8 row-quant ----
// w ≈ s1*q1 + s2*q2, per output row: s1 = max|w|/127, s2 = max|w-s1*q1|/127.
// Residual ≤ s2/2 ≈ max|w|/32k per element; i32 dots are EXACT.
// One wave per row; grid covers padded rows (pad rows -> q=0, s=1).
__global__ __launch_bounds__(256) void quant_rows_k(
    const float* __restrict__ W, const float* __restrict__ g,
    i8* __restrict__ Q1, i8* __restrict__ Q2,
    float* __restrict__ S1, float* __restrict__ S2,
    int K_in, int K_out, int nvalid) {
  int row = blockIdx.x * 4 + (threadIdx.x >> 6);
  int lane = threadIdx.x & 63;
  bool valid = row < nvalid;
  float gm = valid ? g[row] * INV_SQRT_BN : 0.f;
  const float* src = W + (size_t)row * K_in;
  float w[16], r[16];
  const int ne = K_out >> 6;  // 8 or 16
  float mx = 0.f;
  for (int e = 0; e < ne; ++e) {
    int k = lane + (e << 6);
    float v = (valid && k < K_in) ? src[k] * gm : 0.f;
    w[e] = v;
    mx = fmaxf(mx, fabsf(v));
  }
#pragma unroll
  for (int o = 32; o; o >>= 1) mx = fmaxf(mx, __shfl_xor(mx, o));
  float s1 = (mx > 0.f) ? mx * (1.f / 127.f) : 1.f;
  float inv1 = 1.f / s1;
  float mr = 0.f;
  for (int e = 0; e < ne; ++e) {
    float q = fminf(fmaxf(rintf(w[e] * inv1), -127.f), 127.f);
    Q1[(size_t)row * K_out + lane + (e << 6)] = (i8)q;
    float res = fmaf(-s1, q, w[e]);
    r[e] = res;
    mr = fmaxf(mr, fabsf(res));
  }
#pragma unroll
  for (int o = 32; o; o >>= 1) mr = fmaxf(mr, __shfl_xor(mr, o));
  float s2 = (mr > 0.f) ? mr * (1.f / 127.f) : 1.f;
  float inv2 = 1.f / s2;
  for (int e = 0; e < ne; ++e) {
    float q = fminf(fmaxf(rintf(r[e] * inv2), -127.f), 127.f);
    Q2[(size_t)row * K_out + lane + (e << 6)] = (i8)q;
  }
  if (lane == 0) {
    S1[row] = s1;
    S2[row] = s2;
  }
}

// ---------------- GEMM: r9 structure (128x64 tile, BK=128, 2-barrier loop,
// zero-conflict 16B-chunk XOR swizzle, LDS-slab epilogue).
// DUAL=1 (layers): C written as 24-bit fixed point (i16 plane + u8 plane).
// DUAL=0 (final):  C written fp32.
template <int DUAL>
__global__ __launch_bounds__(256, DUAL ? 3 : 4) void gemm_i8(
    const i8* __restrict__ A, const i8* __restrict__ B1q,
    const i8* __restrict__ B2q, const float* __restrict__ S1,
    const float* __restrict__ S2, const float* __restrict__ bias,
    float* __restrict__ C, short* __restrict__ C16, u8* __restrict__ C8,
    int K, int ldc, int ncols) {
  extern __shared__ char smem[];
  char* As = smem;                 // [128][128B]
  char* Bs1 = As + 128 * 128;      // [64][128B]
  char* Bs2 = DUAL ? Bs1 + 64 * 128 : Bs1;

  const int tid = threadIdx.x;
  const int m0 = blockIdx.y * 128;
  const int n0 = blockIdx.x * 64;
  const int lane = tid & 63;
  const int wave = tid >> 6;
  const int wm = (wave & 1) * 64;
  const int wn = (wave >> 1) * 32;
  const int lr = lane & 15;
  const int lq = lane >> 4;  // 0..3

  intx4 acc1[4][2], acc2[DUAL ? 4 : 1][2];
#pragma unroll
  for (int i = 0; i < 4; ++i)
#pragma unroll
    for (int j = 0; j < 2; ++j) {
      intx4 z = {0, 0, 0, 0};
      acc1[i][j] = z;
      if (DUAL) acc2[i][j] = z;
    }

  const int srow = tid >> 3;                    // 0..31
  const int sj = (tid & 7) ^ (srow & 7);        // swizzled global 16B chunk
  const i8* ga = A + (size_t)(m0 + srow) * K + sj * 16;
  const i8* gb1 = B1q + (size_t)(n0 + srow) * K + sj * 16;
  const i8* gb2 = DUAL ? B2q + (size_t)(n0 + srow) * K + sj * 16 : (const i8*)nullptr;
  const int ldso = tid * 16;
  const int sw = lr & 7;                        // row-dependent XOR for reads

  for (int k0 = 0; k0 < K; k0 += 128) {
#pragma unroll
    for (int it = 0; it < 4; ++it)
      g2lds16(ga + (size_t)(it * 32) * K + k0, As + ldso + it * 4096);
#pragma unroll
    for (int it = 0; it < 2; ++it) {
      g2lds16(gb1 + (size_t)(it * 32) * K + k0, Bs1 + ldso + it * 4096);
      if (DUAL) g2lds16(gb2 + (size_t)(it * 32) * K + k0, Bs2 + ldso + it * 4096);
    }
    __syncthreads();
#pragma unroll
    for (int kk = 0; kk < 2; ++kk) {
      const int jc = kk * 4 + lq;               // global 16B k-chunk 0..7
      const int co = ((jc ^ sw) << 4);          // swizzled byte offset
      intx4 af[4];
#pragma unroll
      for (int i = 0; i < 4; ++i)
        af[i] = *(const intx4*)(As + (wm + i * 16 + lr) * 128 + co);
#pragma unroll
      for (int j = 0; j < 2; ++j) {
        const int bo = (wn + j * 16 + lr) * 128 + co;
        intx4 b1 = *(const intx4*)(Bs1 + bo);
#pragma unroll
        for (int i = 0; i < 4; ++i)
          acc1[i][j] = __builtin_amdgcn_mfma_i32_16x16x64_i8(af[i], b1, acc1[i][j], 0, 0, 0);
        if (DUAL) {
          intx4 b2 = *(const intx4*)(Bs2 + bo);
#pragma unroll
          for (int i = 0; i < 4; ++i)
            acc2[i][j] = __builtin_amdgcn_mfma_i32_16x16x64_i8(af[i], b2, acc2[i][j], 0, 0, 0);
        }
      }
    }
    __syncthreads();
  }

  // ---- epilogue: scale-combine, 4 slabs of 32x64 via LDS
  float* Es = (float*)smem;        // [32][68] padded
  float s1v[2], s2v[2], bv[2];
#pragma unroll
  for (int j = 0; j < 2; ++j) {
    int cg = n0 + wn + j * 16 + lr;
    s1v[j] = S1[cg];  // S arrays allocated padded -> always in bounds
    s2v[j] = DUAL ? S2[cg] : 0.f;
    bv[j] = (cg < ncols) ? bias[cg] : 0.f;
  }
#pragma unroll
  for (int s = 0; s < 4; ++s) {
    __syncthreads();
    if ((wave & 1) == (s >> 1)) {
#pragma unroll
      for (int ii = 0; ii < 2; ++ii) {
        int i = (s & 1) * 2 + ii;
#pragma unroll
        for (int j = 0; j < 2; ++j) {
          int cl = wn + j * 16 + lr;
#pragma unroll
          for (int r = 0; r < 4; ++r) {
            float v = fmaf(s1v[j], (float)acc1[i][j][r], bv[j]);
            if (DUAL) v = fmaf(s2v[j], (float)acc2[i][j][r], v);
            Es[(ii * 16 + lq * 4 + r) * 68 + cl] = v;
          }
        }
      }
    }
    __syncthreads();
#pragma unroll
    for (int ps = 0; ps < 2; ++ps) {
      int rl = ps * 16 + (tid >> 4);  // 0..31
      int c4 = (tid & 15) * 4;
      floatx4 v = *(const floatx4*)(Es + rl * 68 + c4);
      int rg = m0 + s * 32 + rl;
      int cg = n0 + c4;
      if (DUAL) {
        // 24-bit fixed point: q = rint(clamp(v)*2^19); hi=q>>8, lo=q&255
        shortx4 hi;
        u32 lo = 0;
#pragma unroll
        for (int r = 0; r < 4; ++r) {
          float vc = fminf(WS_CLAMP, fmaxf(-WS_CLAMP, v[r]));
          int qq = (int)rintf(vc * WS_SCALE);
          hi[r] = (short)(qq >> 8);
          lo |= (u32)(qq & 255) << (8 * r);
        }
        *(shortx4*)(C16 + (size_t)rg * ldc + cg) = hi;
        *(u32*)(C8 + (size_t)rg * ldc + cg) = lo;
      } else {
        if (cg < ncols)
          *(floatx4*)(C + (size_t)rg * ldc + cg) = v;
      }
    }
  }
}

// ---------------- in-place log_softmax over rows of 1944 ----
__global__ __launch_bounds__(256) void logsoftmax_k(float* __restrict__ data) {
  __shared__ float red[8];
  float* p = data + (size_t)blockIdx.x * OUTDIM;
  const int t = threadIdx.x;
  float v[8];
  float mx = -1e30f;
#pragma unroll
  for (int j = 0; j < 8; ++j) {
    int c = t + j * 256;
    v[j] = (c < OUTDIM) ? p[c] : -1e30f;
    mx = fmaxf(mx, v[j]);
  }
#pragma unroll
  for (int o = 32; o > 0; o >>= 1) mx = fmaxf(mx, __shfl_down(mx, o));
  if ((t & 63) == 0) red[t >> 6] = mx;
  __syncthreads();
  mx = fmaxf(fmaxf(red[0], red[1]), fmaxf(red[2], red[3]));
  float s = 0.f;
#pragma unroll
  for (int j = 0; j < 8; ++j) {
    int c = t + j * 256;
    if (c < OUTDIM) s += __expf(v[j] - mx);
  }
#pragma unroll
  for (int o = 32; o > 0; o >>= 1) s += __shfl_down(s, o);
  if ((t & 63) == 0) red[4 + (t >> 6)] = s;
  __syncthreads();
  s = (red[4] + red[5]) + (red[6] + red[7]);
  float lse = mx + __logf(s);
#pragma unroll
  for (int j = 0; j < 8; ++j) {
    int c = t + j * 256;
    if (c < OUTDIM) p[c] = v[j] - lse;
  }
}

extern "C" void kernel_launch(void* const* d_in, const int* in_sizes, int n_in,
                              void* d_out, int out_size, void* d_ws, size_t ws_size,
                              hipStream_t stream) {
  const float* xs = (const float*)d_in[0];
  const float* W0 = (const float*)d_in[1];
  const float* Ws = (const float*)d_in[2];
  const float* taus = (const float*)d_in[3];
  const float* bng = (const float*)d_in[4];
  const float* bnb = (const float*)d_in[5];
  const float* Wf = (const float*)d_in[6];
  const float* fg = (const float*)d_in[7];
  const float* fb = (const float*)d_in[8];
  float* out = (float*)d_out;

  char* p = (char*)d_ws;
  i8* sp0 = (i8*)p;    p += (size_t)MROWS * INPAD;          // 16.4 MB
  i8* sp = (i8*)p;     p += (size_t)MROWS * HID;            // 32.8 MB
  short* ws16 = (short*)p; p += (size_t)MROWS * HID * 2;    // 65.5 MB
  u8* ws8 = (u8*)p;    p += (size_t)MROWS * HID;            // 32.8 MB
  i8* Q1_0 = (i8*)p;   p += (size_t)HID * INPAD;
  i8* Q2_0 = (i8*)p;   p += (size_t)HID * INPAD;
  i8* Q1_l = (i8*)p;   p += (size_t)3 * HID * HID;
  i8* Q2_l = (i8*)p;   p += (size_t)3 * HID * HID;
  i8* Q1_f = (i8*)p;   p += (size_t)OUTPAD * HID;
  i8* Q2_f = (i8*)p;   p += (size_t)OUTPAD * HID;
  float* S1_0 = (float*)p; p += HID * 4;
  float* S2_0 = (float*)p; p += HID * 4;
  float* S1_l = (float*)p; p += 3 * HID * 4;
  float* S2_l = (float*)p; p += 3 * HID * 4;
  float* S1_f = (float*)p; p += OUTPAD * 4;
  float* S2_f = (float*)p; p += OUTPAD * 4;

  input_fsq_k<<<(BATCH * INPAD) / 256, 256, 0, stream>>>(xs, sp0);
  quant_rows_k<<<HID / 4, 256, 0, stream>>>(W0, bng, Q1_0, Q2_0, S1_0, S2_0,
                                            INDIM, INPAD, HID);
  for (int l = 1; l < 4; ++l)
    quant_rows_k<<<HID / 4, 256, 0, stream>>>(
        Ws + (size_t)(l - 1) * HID * HID, bng + l * HID,
        Q1_l + (size_t)(l - 1) * HID * HID, Q2_l + (size_t)(l - 1) * HID * HID,
        S1_l + (l - 1) * HID, S2_l + (l - 1) * HID, HID, HID, HID);
  quant_rows_k<<<OUTPAD / 4, 256, 0, stream>>>(Wf, fg, Q1_f, Q2_f, S1_f, S2_f,
                                               HID, HID, OUTDIM);

  // layer 0 (K = 512)
  gemm_i8<1><<<dim3(HID / 64, MROWS / 128), 256, 32 * 1024, stream>>>(
      sp0, Q1_0, Q2_0, S1_0, S2_0, bnb, nullptr, ws16, ws8, INPAD, HID, HID);
  lif_k<<<(BATCH * HID) / 256, 256, 0, stream>>>(ws16, ws8, taus, sp);
  // layers 1..3 (K = 1024)
  for (int l = 1; l < 4; ++l) {
    gemm_i8<1><<<dim3(HID / 64, MROWS / 128), 256, 32 * 1024, stream>>>(
        sp, Q1_l + (size_t)(l - 1) * HID * HID, Q2_l + (size_t)(l - 1) * HID * HID,
        S1_l + (l - 1) * HID, S2_l + (l - 1) * HID, bnb + l * HID,
        nullptr, ws16, ws8, HID, HID, HID);
    lif_k<<<(BATCH * HID) / 256, 256, 0, stream>>>(ws16, ws8, taus + l * HID, sp);
  }
  // final projection: single-matrix i8, 31 col-blocks (1984 >= 1944) -> d_out
  gemm_i8<0><<<dim3(NBF, MROWS / 128), 256, 24 * 1024, stream>>>(
      sp, Q1_f, (const i8*)nullptr, S1_f, (const float*)nullptr, fb, out,
      (short*)nullptr, (u8*)nullptr, HID, OUTDIM, OUTDIM);
  logsoftmax_k<<<MROWS, 256, 0, stream>>>(out);
}

// Round 11
// 852.390 us; speedup vs baseline: 1.0525x; 1.0525x over previous
//
#include <hip/hip_runtime.h>
#include <hip/hip_bf16.h>
#include <cstddef>

typedef signed char i8;
typedef unsigned int u32;
typedef int intx4 __attribute__((ext_vector_type(4)));
typedef float floatx4 __attribute__((ext_vector_type(4)));

#define T_STEPS 500
#define BATCH 64
#define INDIM 440
#define INPAD 512   // i8 K-pad for layer-0 GEMM (BK=128)
#define HID 1024
#define OUTDIM 1944
#define OUTPAD 2048
#define NBF 31      // final col-blocks: 31*64=1984 >= 1944 (saves 1/32 of work)
#define MROWS 32000  // T*B
#define INV_SQRT_BN 0.9999950000374997f  // 1/sqrt(1+1e-5)
#define CH 20        // scan chunk: 500 = 25*20

__device__ __forceinline__ void g2lds16(const void* g, void* l) {
  __builtin_amdgcn_global_load_lds(
      (const __attribute__((address_space(1))) u32*)g,
      (__attribute__((address_space(3))) u32*)l, 16, 0, 0);
}

// ---------------- input FSQ scan: xs [T,B,440] -> spikes i8 [T*B, 512] ----
__global__ __launch_bounds__(256) void input_fsq_k(const float* __restrict__ xs,
                                                   i8* __restrict__ sp0) {
  int tid = blockIdx.x * 256 + threadIdx.x;  // 64*512
  int b = tid >> 9;
  int i = tid & 511;
  bool act = (i < INDIM);
  const float* src = xs + (size_t)b * INDIM + (act ? i : (INDIM - 1));
  i8* dst = sp0 + (size_t)b * INPAD + i;
  float fact = act ? 1.f : 0.f;
  const int LS = BATCH * INDIM;
  const int SS = BATCH * INPAD;
  float vmem = 0.f;
  float bufA[CH], bufB[CH];
#pragma unroll
  for (int j = 0; j < CH; ++j) bufA[j] = src[(size_t)j * LS];
  for (int it = 0; it < 12; ++it) {
    const int t0 = it * 2 * CH;
#pragma unroll
    for (int j = 0; j < CH; ++j) bufB[j] = src[(size_t)(t0 + CH + j) * LS];
#pragma unroll
    for (int j = 0; j < CH; ++j) {
      vmem += bufA[j] * fact;
      float q = fminf(fmaxf(rintf(vmem), 0.f), 7.f);
      vmem -= q;
      dst[(size_t)(t0 + j) * SS] = (i8)q;
    }
#pragma unroll
    for (int j = 0; j < CH; ++j) bufA[j] = src[(size_t)(t0 + 2 * CH + j) * LS];
#pragma unroll
    for (int j = 0; j < CH; ++j) {
      vmem += bufB[j] * fact;
      float q = fminf(fmaxf(rintf(vmem), 0.f), 7.f);
      vmem -= q;
      dst[(size_t)(t0 + CH + j) * SS] = (i8)q;
    }
  }
  const int t0 = 24 * CH;
#pragma unroll
  for (int j = 0; j < CH; ++j) {
    vmem += bufA[j] * fact;
    float q = fminf(fmaxf(rintf(vmem), 0.f), 7.f);
    vmem -= q;
    dst[(size_t)(t0 + j) * SS] = (i8)q;
  }
}

// ---------------- LIF scan: ws fp32 [T*B, 1024] -> spikes i8 ----
__global__ __launch_bounds__(256) void lif_k(const float* __restrict__ ws,
                                             const float* __restrict__ taus,
                                             i8* __restrict__ sp) {
  int tid = blockIdx.x * 256 + threadIdx.x;  // 65536 = B*HID
  float tau = taus[tid & (HID - 1)];
  const float* src = ws + tid;
  i8* dst = sp + tid;
  const int S = BATCH * HID;
  float syn = 0.f, vmem = 0.f;
  float bufA[CH], bufB[CH];
#pragma unroll
  for (int j = 0; j < CH; ++j) bufA[j] = src[(size_t)j * S];
  for (int it = 0; it < 12; ++it) {
    const int t0 = it * 2 * CH;
#pragma unroll
    for (int j = 0; j < CH; ++j) bufB[j] = src[(size_t)(t0 + CH + j) * S];
#pragma unroll
    for (int j = 0; j < CH; ++j) {
      syn = fmaf(tau, syn, bufA[j]);
      vmem += syn;
      float q = fminf(fmaxf(rintf(vmem), 0.f), 7.f);
      vmem -= q;
      dst[(size_t)(t0 + j) * S] = (i8)q;
    }
#pragma unroll
    for (int j = 0; j < CH; ++j) bufA[j] = src[(size_t)(t0 + 2 * CH + j) * S];
#pragma unroll
    for (int j = 0; j < CH; ++j) {
      syn = fmaf(tau, syn, bufB[j]);
      vmem += syn;
      float q = fminf(fmaxf(rintf(vmem), 0.f), 7.f);
      vmem -= q;
      dst[(size_t)(t0 + CH + j) * S] = (i8)q;
    }
  }
  const int t0 = 24 * CH;
#pragma unroll
  for (int j = 0; j < CH; ++j) {
    syn = fmaf(tau, syn, bufA[j]);
    vmem += syn;
    float q = fminf(fmaxf(rintf(vmem), 0.f), 7.f);
    vmem -= q;
    dst[(size_t)(t0 + j) * S] = (i8)q;
  }
}

// ---------------- weight prep: fold BN gamma, dual int8 row-quant ----
// w ≈ s1*q1 + s2*q2, per output row: s1 = max|w|/127, s2 = max|w-s1*q1|/127.
// Residual ≤ s2/2 ≈ max|w|/32k per element; i32 dots are EXACT.
// One wave per row; grid covers padded rows (pad rows -> q=0, s=1).
__global__ __launch_bounds__(256) void quant_rows_k(
    const float* __restrict__ W, const float* __restrict__ g,
    i8* __restrict__ Q1, i8* __restrict__ Q2,
    float* __restrict__ S1, float* __restrict__ S2,
    int K_in, int K_out, int nvalid) {
  int row = blockIdx.x * 4 + (threadIdx.x >> 6);
  int lane = threadIdx.x & 63;
  bool valid = row < nvalid;
  float gm = valid ? g[row] * INV_SQRT_BN : 0.f;
  const float* src = W + (size_t)row * K_in;
  float w[16], r[16];
  const int ne = K_out >> 6;  // 8 or 16
  float mx = 0.f;
  for (int e = 0; e < ne; ++e) {
    int k = lane + (e << 6);
    float v = (valid && k < K_in) ? src[k] * gm : 0.f;
    w[e] = v;
    mx = fmaxf(mx, fabsf(v));
  }
#pragma unroll
  for (int o = 32; o; o >>= 1) mx = fmaxf(mx, __shfl_xor(mx, o));
  float s1 = (mx > 0.f) ? mx * (1.f / 127.f) : 1.f;
  float inv1 = 1.f / s1;
  float mr = 0.f;
  for (int e = 0; e < ne; ++e) {
    float q = fminf(fmaxf(rintf(w[e] * inv1), -127.f), 127.f);
    Q1[(size_t)row * K_out + lane + (e << 6)] = (i8)q;
    float res = fmaf(-s1, q, w[e]);
    r[e] = res;
    mr = fmaxf(mr, fabsf(res));
  }
#pragma unroll
  for (int o = 32; o; o >>= 1) mr = fmaxf(mr, __shfl_xor(mr, o));
  float s2 = (mr > 0.f) ? mr * (1.f / 127.f) : 1.f;
  float inv2 = 1.f / s2;
  for (int e = 0; e < ne; ++e) {
    float q = fminf(fmaxf(rintf(r[e] * inv2), -127.f), 127.f);
    Q2[(size_t)row * K_out + lane + (e << 6)] = (i8)q;
  }
  if (lane == 0) {
    S1[row] = s1;
    S2[row] = s2;
  }
}

// ---------------- GEMM: r9 structure (128x64 tile, BK=128, 2-barrier loop,
// zero-conflict 16B-chunk XOR swizzle, LDS-slab epilogue) + XCD-affinity
// chunked remap.  Default round-robin puts the 16 col-blocks that share one
// 131KB A-panel on 8 DIFFERENT XCDs -> panel replicated in 8 L2s, drain
// latency = L3 (~500cy).  Remap (bijective bit-permute within 128-id chunks,
// tail identity): physical slot r -> logical (r&7)*16 + r/8, so each XCD owns
// complete y-rows -> A-panel fetched once into its L2, 15 warm hits.
template <int DUAL>
__global__ __launch_bounds__(256, DUAL ? 3 : 4) void gemm_i8(
    const i8* __restrict__ A, const i8* __restrict__ B1q,
    const i8* __restrict__ B2q, const float* __restrict__ S1,
    const float* __restrict__ S2, const float* __restrict__ bias,
    float* __restrict__ C, int K, int ldc, int ncols) {
  extern __shared__ char smem[];
  char* As = smem;                 // [128][128B]
  char* Bs1 = As + 128 * 128;      // [64][128B]
  char* Bs2 = DUAL ? Bs1 + 64 * 128 : Bs1;

  const int tid = threadIdx.x;
  // ---- XCD-affinity remap (bijective; see header comment)
  const int nbx = gridDim.x;
  const int total = nbx * gridDim.y;
  int pid = blockIdx.y * nbx + blockIdx.x;
  int lin = (pid < (total & ~127))
                ? ((pid & ~127) | ((pid & 7) << 4) | ((pid & 127) >> 3))
                : pid;
  const int m0 = (lin / nbx) * 128;
  const int n0 = (lin % nbx) * 64;
  const int lane = tid & 63;
  const int wave = tid >> 6;
  const int wm = (wave & 1) * 64;
  const int wn = (wave >> 1) * 32;
  const int lr = lane & 15;
  const int lq = lane >> 4;  // 0..3

  intx4 acc1[4][2], acc2[DUAL ? 4 : 1][2];
#pragma unroll
  for (int i = 0; i < 4; ++i)
#pragma unroll
    for (int j = 0; j < 2; ++j) {
      intx4 z = {0, 0, 0, 0};
      acc1[i][j] = z;
      if (DUAL) acc2[i][j] = z;
    }

  const int srow = tid >> 3;                    // 0..31
  const int sj = (tid & 7) ^ (srow & 7);        // swizzled global 16B chunk
  const i8* ga = A + (size_t)(m0 + srow) * K + sj * 16;
  const i8* gb1 = B1q + (size_t)(n0 + srow) * K + sj * 16;
  const i8* gb2 = DUAL ? B2q + (size_t)(n0 + srow) * K + sj * 16 : (const i8*)nullptr;
  const int ldso = tid * 16;
  const int sw = lr & 7;                        // row-dependent XOR for reads

  for (int k0 = 0; k0 < K; k0 += 128) {
#pragma unroll
    for (int it = 0; it < 4; ++it)
      g2lds16(ga + (size_t)(it * 32) * K + k0, As + ldso + it * 4096);
#pragma unroll
    for (int it = 0; it < 2; ++it) {
      g2lds16(gb1 + (size_t)(it * 32) * K + k0, Bs1 + ldso + it * 4096);
      if (DUAL) g2lds16(gb2 + (size_t)(it * 32) * K + k0, Bs2 + ldso + it * 4096);
    }
    __syncthreads();
#pragma unroll
    for (int kk = 0; kk < 2; ++kk) {
      const int jc = kk * 4 + lq;               // global 16B k-chunk 0..7
      const int co = ((jc ^ sw) << 4);          // swizzled byte offset
      intx4 af[4];
#pragma unroll
      for (int i = 0; i < 4; ++i)
        af[i] = *(const intx4*)(As + (wm + i * 16 + lr) * 128 + co);
#pragma unroll
      for (int j = 0; j < 2; ++j) {
        const int bo = (wn + j * 16 + lr) * 128 + co;
        intx4 b1 = *(const intx4*)(Bs1 + bo);
#pragma unroll
        for (int i = 0; i < 4; ++i)
          acc1[i][j] = __builtin_amdgcn_mfma_i32_16x16x64_i8(af[i], b1, acc1[i][j], 0, 0, 0);
        if (DUAL) {
          intx4 b2 = *(const intx4*)(Bs2 + bo);
#pragma unroll
          for (int i = 0; i < 4; ++i)
            acc2[i][j] = __builtin_amdgcn_mfma_i32_16x16x64_i8(af[i], b2, acc2[i][j], 0, 0, 0);
        }
      }
    }
    __syncthreads();
  }

  // ---- epilogue: scale-combine, 4 slabs of 32x64 via LDS, float4 stores
  float* Es = (float*)smem;        // [32][68] padded
  float s1v[2], s2v[2], bv[2];
#pragma unroll
  for (int j = 0; j < 2; ++j) {
    int cg = n0 + wn + j * 16 + lr;
    s1v[j] = S1[cg];  // S arrays allocated padded -> always in bounds
    s2v[j] = DUAL ? S2[cg] : 0.f;
    bv[j] = (cg < ncols) ? bias[cg] : 0.f;
  }
#pragma unroll
  for (int s = 0; s < 4; ++s) {
    __syncthreads();
    if ((wave & 1) == (s >> 1)) {
#pragma unroll
      for (int ii = 0; ii < 2; ++ii) {
        int i = (s & 1) * 2 + ii;
#pragma unroll
        for (int j = 0; j < 2; ++j) {
          int cl = wn + j * 16 + lr;
#pragma unroll
          for (int r = 0; r < 4; ++r) {
            float v = fmaf(s1v[j], (float)acc1[i][j][r], bv[j]);
            if (DUAL) v = fmaf(s2v[j], (float)acc2[i][j][r], v);
            Es[(ii * 16 + lq * 4 + r) * 68 + cl] = v;
          }
        }
      }
    }
    __syncthreads();
#pragma unroll
    for (int ps = 0; ps < 2; ++ps) {
      int rl = ps * 16 + (tid >> 4);  // 0..31
      int c4 = (tid & 15) * 4;
      floatx4 v = *(const floatx4*)(Es + rl * 68 + c4);
      int rg = m0 + s * 32 + rl;
      int cg = n0 + c4;
      if (cg < ncols)
        *(floatx4*)(C + (size_t)rg * ldc + cg) = v;
    }
  }
}

// ---------------- in-place log_softmax over rows of 1944 ----
__global__ __launch_bounds__(256) void logsoftmax_k(float* __restrict__ data) {
  __shared__ float red[8];
  float* p = data + (size_t)blockIdx.x * OUTDIM;
  const int t = threadIdx.x;
  float v[8];
  float mx = -1e30f;
#pragma unroll
  for (int j = 0; j < 8; ++j) {
    int c = t + j * 256;
    v[j] = (c < OUTDIM) ? p[c] : -1e30f;
    mx = fmaxf(mx, v[j]);
  }
#pragma unroll
  for (int o = 32; o > 0; o >>= 1) mx = fmaxf(mx, __shfl_down(mx, o));
  if ((t & 63) == 0) red[t >> 6] = mx;
  __syncthreads();
  mx = fmaxf(fmaxf(red[0], red[1]), fmaxf(red[2], red[3]));
  float s = 0.f;
#pragma unroll
  for (int j = 0; j < 8; ++j) {
    int c = t + j * 256;
    if (c < OUTDIM) s += __expf(v[j] - mx);
  }
#pragma unroll
  for (int o = 32; o > 0; o >>= 1) s += __shfl_down(s, o);
  if ((t & 63) == 0) red[4 + (t >> 6)] = s;
  __syncthreads();
  s = (red[4] + red[5]) + (red[6] + red[7]);
  float lse = mx + __logf(s);
#pragma unroll
  for (int j = 0; j < 8; ++j) {
    int c = t + j * 256;
    if (c < OUTDIM) p[c] = v[j] - lse;
  }
}

extern "C" void kernel_launch(void* const* d_in, const int* in_sizes, int n_in,
                              void* d_out, int out_size, void* d_ws, size_t ws_size,
                              hipStream_t stream) {
  const float* xs = (const float*)d_in[0];
  const float* W0 = (const float*)d_in[1];
  const float* Ws = (const float*)d_in[2];
  const float* taus = (const float*)d_in[3];
  const float* bng = (const float*)d_in[4];
  const float* bnb = (const float*)d_in[5];
  const float* Wf = (const float*)d_in[6];
  const float* fg = (const float*)d_in[7];
  const float* fb = (const float*)d_in[8];
  float* out = (float*)d_out;

  char* p = (char*)d_ws;
  i8* sp0 = (i8*)p;    p += (size_t)MROWS * INPAD;          // 16.4 MB
  i8* sp = (i8*)p;     p += (size_t)MROWS * HID;            // 32.8 MB
  float* wsb = (float*)p; p += (size_t)MROWS * HID * 4;     // 131 MB
  i8* Q1_0 = (i8*)p;   p += (size_t)HID * INPAD;
  i8* Q2_0 = (i8*)p;   p += (size_t)HID * INPAD;
  i8* Q1_l = (i8*)p;   p += (size_t)3 * HID * HID;
  i8* Q2_l = (i8*)p;   p += (size_t)3 * HID * HID;
  i8* Q1_f = (i8*)p;   p += (size_t)OUTPAD * HID;
  i8* Q2_f = (i8*)p;   p += (size_t)OUTPAD * HID;
  float* S1_0 = (float*)p; p += HID * 4;
  float* S2_0 = (float*)p; p += HID * 4;
  float* S1_l = (float*)p; p += 3 * HID * 4;
  float* S2_l = (float*)p; p += 3 * HID * 4;
  float* S1_f = (float*)p; p += OUTPAD * 4;
  float* S2_f = (float*)p; p += OUTPAD * 4;

  input_fsq_k<<<(BATCH * INPAD) / 256, 256, 0, stream>>>(xs, sp0);
  quant_rows_k<<<HID / 4, 256, 0, stream>>>(W0, bng, Q1_0, Q2_0, S1_0, S2_0,
                                            INDIM, INPAD, HID);
  for (int l = 1; l < 4; ++l)
    quant_rows_k<<<HID / 4, 256, 0, stream>>>(
        Ws + (size_t)(l - 1) * HID * HID, bng + l * HID,
        Q1_l + (size_t)(l - 1) * HID * HID, Q2_l + (size_t)(l - 1) * HID * HID,
        S1_l + (l - 1) * HID, S2_l + (l - 1) * HID, HID, HID, HID);
  quant_rows_k<<<OUTPAD / 4, 256, 0, stream>>>(Wf, fg, Q1_f, Q2_f, S1_f, S2_f,
                                               HID, HID, OUTDIM);

  // layer 0 (K = 512)
  gemm_i8<1><<<dim3(HID / 64, MROWS / 128), 256, 32 * 1024, stream>>>(
      sp0, Q1_0, Q2_0, S1_0, S2_0, bnb, wsb, INPAD, HID, HID);
  lif_k<<<(BATCH * HID) / 256, 256, 0, stream>>>(wsb, taus, sp);
  // layers 1..3 (K = 1024)
  for (int l = 1; l < 4; ++l) {
    gemm_i8<1><<<dim3(HID / 64, MROWS / 128), 256, 32 * 1024, stream>>>(
        sp, Q1_l + (size_t)(l - 1) * HID * HID, Q2_l + (size_t)(l - 1) * HID * HID,
        S1_l + (l - 1) * HID, S2_l + (l - 1) * HID, bnb + l * HID, wsb,
        HID, HID, HID);
    lif_k<<<(BATCH * HID) / 256, 256, 0, stream>>>(wsb, taus + l * HID, sp);
  }
  // final projection: single-matrix i8, 31 col-blocks (1984 >= 1944) -> d_out
  gemm_i8<0><<<dim3(NBF, MROWS / 128), 256, 24 * 1024, stream>>>(
      sp, Q1_f, (const i8*)nullptr, S1_f, (const float*)nullptr, fb, out,
      HID, OUTDIM, OUTDIM);
  logsoftmax_k<<<MROWS, 256, 0, stream>>>(out);
}